// Round 12
// baseline (452.110 us; speedup 1.0000x reference)
//
#include <hip/hip_runtime.h>

#define NV   50000
#define NR   5
#define NT   8
#define CIN  64
#define COUT 64
#define BARY (NR*NT*3)      // 120
#define BK_ELEMS (NR*CIN*NT*COUT)   // 163840 fp16 (320 KB) — L2-resident
#define BM2  64
#define NBLK2 ((NV + BM2 - 1) / BM2)   // 782
#define NCH  80             // chunks: (j 0..7) x (icc 0..9), K=32 each

#define WL_BYTES 262144
#define SIG16_BYTES (NV*CIN*2)                            // 6.4 MB
#define WS_NEED8 (WL_BYTES + 2u*BK_ELEMS + SIG16_BYTES)   // ~7.0 MB

typedef _Float16 f16x8 __attribute__((ext_vector_type(8)));
typedef _Float16 f16x4 __attribute__((ext_vector_type(4)));
typedef float    f32x4 __attribute__((ext_vector_type(4)));

// ---------- K0a: kernel -> fp16, MFMA-FRAGMENT order ----------
// bkf[((icc*8 + m)*64 + lane)*32 + nf*8 + h] = B[col=m*64+nf*16+(lane&15)][ck=(lane>>4)*8+h]
// so a wave's 4 fragments for (icc,m) are ONE 4KB contiguous block (64 B/lane).
__global__ __launch_bounds__(256) void build_bk8(
    const float* __restrict__ kern, _Float16* __restrict__ bkf)
{
    int e    = blockIdx.x * 256 + threadIdx.x;
    int h    = e & 7;
    int nf   = (e >> 3) & 3;
    int lane = (e >> 5) & 63;
    int m    = (e >> 11) & 7;
    int icc  = e >> 14;
    int d    = nf * 16 + (lane & 15);
    int ck   = (lane >> 4) * 8 + h;
    int c    = (icc & 1) * 32 + ck;
    int i    = icc >> 1;
    bkf[e] = (_Float16)kern[((i * NT + m) * CIN + c) * COUT + d];
}

// ---------- K0b: signal -> fp16 ----------
__global__ __launch_bounds__(256) void build_sig16(
    const float* __restrict__ signal, _Float16* __restrict__ sig16)
{
    int e = blockIdx.x * 256 + threadIdx.x;
    sig16[e] = (_Float16)signal[e];
}

// ---------- main v8: B direct L2->reg (fragment order), raw barriers, swizzled A ----------
__global__ __launch_bounds__(512, 4) void geo_mfma8(
    const float* __restrict__ bary_w,
    const int*   __restrict__ bary_idx,
    const _Float16* __restrict__ sig16,
    const _Float16* __restrict__ bkf,
    float* __restrict__ out,
    int*   __restrict__ wl)
{
    // A tile 4 KB, XOR-swizzled: idx ^= g<<4 -> verified conflict-free R+W
    __shared__ __align__(16) _Float16 AxsF[4 * BM2 * 8];
    __shared__ float nrm[BM2][NT];
    __shared__ int   besti[BM2];

    const int tid  = threadIdx.x;
    const int lane = tid & 63;
    const int wn   = tid >> 6;         // wave wn owns rotation k=wn
    const int g    = lane >> 4;
    const int l15  = lane & 15;
    const int vbase = blockIdx.x * BM2;

    // A-staging mapping: thread -> (vertex vt, ck-quad cq)
    const int vt = tid >> 3;
    const int cq = tid & 7;
    const int v_mine = vbase + vt;
    const bool v_ok = (v_mine < NV);

    f32x4 acc[4][4];
    {
        f32x4 z = {0.f, 0.f, 0.f, 0.f};
        #pragma unroll
        for (int mf = 0; mf < 4; ++mf)
            #pragma unroll
            for (int nf = 0; nf < 4; ++nf) acc[mf][nf] = z;
    }

    struct Gen { float w0, w1, w2; int i0, i1, i2; };
    auto LOADGEN = [&](int it2) -> Gen {
        Gen gg;
        const int itc = (it2 < NCH) ? it2 : (NCH - 1);
        const int j2   = itc / 10;
        const int icc2 = itc - j2 * 10;
        const int i2   = icc2 >> 1;
        if (v_ok) {
            const int base = v_mine * BARY + (i2 * NT + j2) * 3;
            gg.w0 = bary_w[base + 0];
            gg.w1 = bary_w[base + 1];
            gg.w2 = bary_w[base + 2];
            gg.i0 = bary_idx[base + 0];
            gg.i1 = bary_idx[base + 1];
            gg.i2 = bary_idx[base + 2];
        } else {
            gg.w0 = gg.w1 = gg.w2 = 0.f;
            gg.i0 = gg.i1 = gg.i2 = 0;
        }
        return gg;
    };

    f16x4 sA0, sA1, sA2, sB0, sB1, sB2;
    auto SIGLOAD = [&](const Gen& gg, int it2, f16x4& o0, f16x4& o1, f16x4& o2) {
        const int itc = (it2 < NCH) ? it2 : (NCH - 1);
        const int icc2 = itc - (itc / 10) * 10;
        const int coff = (icc2 & 1) * 32 + cq * 4;
        o0 = *(const f16x4*)(sig16 + gg.i0 * CIN + coff);
        o1 = *(const f16x4*)(sig16 + gg.i1 * CIN + coff);
        o2 = *(const f16x4*)(sig16 + gg.i2 * CIN + coff);
    };

    // B fragments straight from L2 (fragment-ordered, 64 B/lane contiguous)
    auto BFRAG = [&](int it2, f16x8& b0, f16x8& b1, f16x8& b2, f16x8& b3) {
        const int j2   = it2 / 10;
        const int icc2 = it2 - j2 * 10;
        const int m2   = (j2 + wn) & 7;
        const _Float16* src = bkf + ((icc2 * 8 + m2) * 64 + lane) * 32;
        b0 = *(const f16x8*)(src + 0);
        b1 = *(const f16x8*)(src + 8);
        b2 = *(const f16x8*)(src + 16);
        b3 = *(const f16x8*)(src + 24);
    };

    // ---- prologue ----
    Gen g0 = LOADGEN(0);
    Gen g1 = LOADGEN(1);
    SIGLOAD(g0, 0, sA0, sA1, sA2);
    f16x8 bc0, bc1, bc2, bc3, bn0, bn1, bn2, bn3;
    BFRAG(0, bc0, bc1, bc2, bc3);

    const int gw = cq >> 1;
    const int widx = (gw * 512 + vt * 8 + (cq & 1) * 4) ^ (gw << 4);

    for (int it = 0; it < NCH; ++it) {
        // ---- phase1: x(it) from regs -> swizzled Axs; refill pipelines ----
        {
            f16x4 hv;
            #pragma unroll
            for (int e = 0; e < 4; ++e) {
                float xf = g0.w0 * (float)sA0[e]
                         + g0.w1 * (float)sA1[e]
                         + g0.w2 * (float)sA2[e];
                hv[e] = (_Float16)xf;
            }
            *(f16x4*)&AxsF[widx] = hv;
        }
        SIGLOAD(g1, it + 1, sB0, sB1, sB2);
        g0 = g1;
        g1 = LOADGEN(it + 2);

        // raw barrier: drain ONLY lgkm (the ds_write); global loads stay in flight
        asm volatile("s_waitcnt lgkmcnt(0)" ::: "memory");
        __builtin_amdgcn_s_barrier();
        asm volatile("" ::: "memory");

        // ---- phase2: issue B(it+1); MFMA from registers + swizzled A ----
        if (it + 1 < NCH) BFRAG(it + 1, bn0, bn1, bn2, bn3);

        f16x8 af[4];
        #pragma unroll
        for (int mf = 0; mf < 4; ++mf) {
            const int row = mf * 16 + l15;
            af[mf] = *(const f16x8*)&AxsF[(g * 512 + row * 8) ^ (g << 4)];
        }

        #pragma unroll
        for (int mf = 0; mf < 4; ++mf) {
            acc[mf][0] = __builtin_amdgcn_mfma_f32_16x16x32_f16(af[mf], bc0, acc[mf][0], 0, 0, 0);
            acc[mf][1] = __builtin_amdgcn_mfma_f32_16x16x32_f16(af[mf], bc1, acc[mf][1], 0, 0, 0);
            acc[mf][2] = __builtin_amdgcn_mfma_f32_16x16x32_f16(af[mf], bc2, acc[mf][2], 0, 0, 0);
            acc[mf][3] = __builtin_amdgcn_mfma_f32_16x16x32_f16(af[mf], bc3, acc[mf][3], 0, 0, 0);
        }

        // raw barrier: afrag reads are complete (reg-dep before MFMA issue),
        // so Axs is safe to overwrite next phase1; nothing to drain.
        asm volatile("" ::: "memory");
        __builtin_amdgcn_s_barrier();
        asm volatile("" ::: "memory");

        bc0 = bn0; bc1 = bn1; bc2 = bn2; bc3 = bn3;
        sA0 = sB0; sA1 = sB1; sA2 = sB2;
    }

    // ---- epilogue: wave wn owns rotation wn; norms per row ----
    #pragma unroll
    for (int mf = 0; mf < 4; ++mf)
        #pragma unroll
        for (int ri = 0; ri < 4; ++ri) {
            float s = 0.f;
            #pragma unroll
            for (int nf = 0; nf < 4; ++nf) {
                float vv = acc[mf][nf][ri];
                s = fmaf(vv, vv, s);
            }
            #pragma unroll
            for (int off = 1; off < 16; off <<= 1)
                s += __shfl_xor(s, off);
            if (l15 == 0) nrm[mf * 16 + g * 4 + ri][wn] = s;
        }
    __syncthreads();

    if (tid < BM2) {
        const int v = vbase + tid;
        float bn = nrm[tid][0];
        float sec = -1e30f;
        int best = 0;
        #pragma unroll
        for (int k = 1; k < NT; ++k) {
            float nv = nrm[tid][k];
            if (nv > bn)       { sec = bn; bn = nv; best = k; }
            else if (nv > sec) { sec = nv; }
        }
        // fp16-input norm^2 error ~1.2e-2 sigma; ~6 sigma + rel term
        const bool flag = (bn - sec) <= (7e-2f + 2e-3f * bn);
        besti[tid] = flag ? -1 : best;
        if (flag && v < NV) { int p = atomicAdd(wl, 1); wl[1 + p] = v; }
    }
    __syncthreads();

    #pragma unroll
    for (int mf = 0; mf < 4; ++mf)
        #pragma unroll
        for (int ri = 0; ri < 4; ++ri) {
            const int row = mf * 16 + g * 4 + ri;
            const int v   = vbase + row;
            const int bsel = (v < NV) ? besti[row] : -1;
            if (bsel == wn) {
                #pragma unroll
                for (int nf = 0; nf < 4; ++nf) {
                    const int d = nf * 16 + l15;
                    out[v * COUT + d] = fmaxf(acc[mf][nf][ri], 0.0f);
                }
            }
        }
}

// ---------- parallel fp64 refine: one BLOCK (4 waves) per vertex ----------
__global__ __launch_bounds__(256) void geo_refine_f64p(
    const float* __restrict__ signal,
    const float* __restrict__ bary_w,
    const int*   __restrict__ bary_idx,
    const float* __restrict__ kern,
    float*       __restrict__ out,
    const int*   __restrict__ wl,
    int nall)
{
    __shared__ __align__(16) float xs[NR][CIN][NT];
    __shared__ double part[4][NT][COUT];
    __shared__ double convl[NT][COUT];
    __shared__ double nks[NT];
    __shared__ int bestS;

    const int tid  = threadIdx.x;
    const int wave = tid >> 6;
    const int lane = tid & 63;
    const int count = wl ? wl[0] : nall;

    for (int w = blockIdx.x; w < count; w += gridDim.x) {
        const int v = wl ? wl[1 + w] : w;

        for (int ij = wave; ij < NR * NT; ij += 4) {
            const int i = ij >> 3, j = ij & 7;
            const int base = v * BARY + ij * 3;
            const float w0 = bary_w[base], w1 = bary_w[base+1], w2 = bary_w[base+2];
            const int   i0 = bary_idx[base], i1 = bary_idx[base+1], i2 = bary_idx[base+2];
            xs[i][lane][j] = w0 * signal[i0*CIN + lane]
                           + w1 * signal[i1*CIN + lane]
                           + w2 * signal[i2*CIN + lane];
        }
        __syncthreads();

        double acc[NT];
        #pragma unroll
        for (int k = 0; k < NT; ++k) acc[k] = 0.0;

        for (int r = wave * 80; r < wave * 80 + 80; ++r) {
            const int i = r >> 6, c = r & 63;
            const float4 xa = *reinterpret_cast<const float4*>(&xs[i][c][0]);
            const float4 xb = *reinterpret_cast<const float4*>(&xs[i][c][4]);
            const double x8[NT] = {(double)xa.x, (double)xa.y, (double)xa.z, (double)xa.w,
                                   (double)xb.x, (double)xb.y, (double)xb.z, (double)xb.w};
            #pragma unroll
            for (int mm = 0; mm < NT; ++mm) {
                const double kv = (double)kern[((i * NT + mm) * CIN + c) * COUT + lane];
                #pragma unroll
                for (int k = 0; k < NT; ++k)
                    acc[k] = fma(x8[(mm - k + NT) & (NT - 1)], kv, acc[k]);
            }
        }
        #pragma unroll
        for (int k = 0; k < NT; ++k) part[wave][k][lane] = acc[k];
        __syncthreads();

        for (int kd = tid; kd < NT * COUT; kd += 256) {
            const int k = kd >> 6, d = kd & 63;
            convl[k][d] = ((part[0][k][d] + part[1][k][d])
                         + (part[2][k][d] + part[3][k][d]));
        }
        __syncthreads();

        for (int k = wave; k < NT; k += 4) {
            double n = convl[k][lane] * convl[k][lane];
            #pragma unroll
            for (int off = 32; off >= 1; off >>= 1) n += __shfl_xor(n, off);
            if (lane == 0) nks[k] = n;
        }
        __syncthreads();

        if (tid == 0) {
            int best = 0; double bn = nks[0];
            #pragma unroll
            for (int k = 1; k < NT; ++k)
                if (nks[k] > bn) { bn = nks[k]; best = k; }
            bestS = best;
        }
        __syncthreads();

        if (tid < COUT) out[v * COUT + tid] = fmaxf((float)convl[bestS][tid], 0.0f);
        __syncthreads();
    }
}

extern "C" void kernel_launch(void* const* d_in, const int* in_sizes, int n_in,
                              void* d_out, int out_size, void* d_ws, size_t ws_size,
                              hipStream_t stream) {
    const float* signal   = (const float*)d_in[0];
    const float* bary_w   = (const float*)d_in[1];
    const int*   bary_idx = (const int*)d_in[2];
    const float* kern     = (const float*)d_in[3];
    float* out = (float*)d_out;

    if (ws_size >= (size_t)WS_NEED8) {
        int* wl = (int*)d_ws;
        _Float16* bkf   = (_Float16*)((char*)d_ws + WL_BYTES);
        _Float16* sig16 = (_Float16*)((char*)d_ws + WL_BYTES + 2u * BK_ELEMS);
        hipMemsetAsync(wl, 0, sizeof(int), stream);
        build_bk8<<<dim3(BK_ELEMS / 256), dim3(256), 0, stream>>>(kern, bkf);
        build_sig16<<<dim3(NV * CIN / 256), dim3(256), 0, stream>>>(signal, sig16);
        geo_mfma8<<<dim3(NBLK2), dim3(512), 0, stream>>>(
            bary_w, bary_idx, sig16, bkf, out, wl);
        geo_refine_f64p<<<dim3(1024), dim3(256), 0, stream>>>(
            signal, bary_w, bary_idx, kern, out, wl, 0);
    } else {
        geo_refine_f64p<<<dim3(1024), dim3(256), 0, stream>>>(
            signal, bary_w, bary_idx, kern, out, nullptr, NV);
    }
}